// Round 4
// baseline (59.383 us; speedup 1.0000x reference)
//
#include <hip/hip_runtime.h>
#include <math.h>

// ---------------------------------------------------------------------------
// DRR forward projection, LDS-brick version.
//
// setup_k: folds all small linear algebra into 21 per-batch floats
//   vox(s) = p0 + alpha_s*(A1@pixh), ray = A2@pixh, seglen=|ray|/S;
//   also zeroes a 256B "zero page" in d_ws (DMA target for OOB groups).
//
// drr3: block = 16x16 pixels, 1 px/thread, 4 waves. Ray marched in chunks of
// 5 steps. Per chunk: block-reduced AABB of (support-clamped) sample coords;
// brick staged global->LDS via global_load_lds dwordx4 (z-base 4-aligned so
// 16B groups are wholly in/out of volume; OOB groups read a zero page ->
// staged zeros == reference inb gating, exactly). Double-buffered bricks:
// DMA(k+1) issued before sampling(k). act predicate (raw==clamped && s<s_end)
// kills out-of-support steps exactly. Block-uniform global-gather fallback if
// a brick exceeds capacity (not taken for this input's geometry).
// ---------------------------------------------------------------------------

#define TSZ 16
#define CST 5
#define BXA 24
#define BYA 25
#define BZW 20
#define BUFN (BXA*BYA*BZW + 256)   // 12256 floats per buffer (incl DMA overshoot pad)

__device__ __forceinline__ void stage16(const float* g, float* l) {
    __builtin_amdgcn_global_load_lds(
        (const __attribute__((address_space(1))) unsigned int*)g,
        (__attribute__((address_space(3))) unsigned int*)l,
        16, 0, 0);
}

__device__ __forceinline__ void inv4x4(const float* m, float* inv) {
    inv[0]  =  m[5]*m[10]*m[15] - m[5]*m[11]*m[14] - m[9]*m[6]*m[15] + m[9]*m[7]*m[14] + m[13]*m[6]*m[11] - m[13]*m[7]*m[10];
    inv[4]  = -m[4]*m[10]*m[15] + m[4]*m[11]*m[14] + m[8]*m[6]*m[15] - m[8]*m[7]*m[14] - m[12]*m[6]*m[11] + m[12]*m[7]*m[10];
    inv[8]  =  m[4]*m[9]*m[15]  - m[4]*m[11]*m[13] - m[8]*m[5]*m[15] + m[8]*m[7]*m[13] + m[12]*m[5]*m[11] - m[12]*m[7]*m[9];
    inv[12] = -m[4]*m[9]*m[14]  + m[4]*m[10]*m[13] + m[8]*m[5]*m[14] - m[8]*m[6]*m[13] - m[12]*m[5]*m[10] + m[12]*m[6]*m[9];
    inv[1]  = -m[1]*m[10]*m[15] + m[1]*m[11]*m[14] + m[9]*m[2]*m[15] - m[9]*m[3]*m[14] - m[13]*m[2]*m[11] + m[13]*m[3]*m[10];
    inv[5]  =  m[0]*m[10]*m[15] - m[0]*m[11]*m[14] - m[8]*m[2]*m[15] + m[8]*m[3]*m[14] + m[12]*m[2]*m[11] - m[12]*m[3]*m[10];
    inv[9]  = -m[0]*m[9]*m[15]  + m[0]*m[11]*m[13] + m[8]*m[1]*m[15] - m[8]*m[3]*m[13] - m[12]*m[1]*m[11] + m[12]*m[3]*m[9];
    inv[13] =  m[0]*m[9]*m[14]  - m[0]*m[10]*m[13] - m[8]*m[1]*m[14] + m[8]*m[2]*m[13] + m[12]*m[1]*m[10] - m[12]*m[2]*m[9];
    inv[2]  =  m[1]*m[6]*m[15]  - m[1]*m[7]*m[14]  - m[5]*m[2]*m[15] + m[5]*m[3]*m[14] + m[13]*m[2]*m[7]  - m[13]*m[3]*m[6];
    inv[6]  = -m[0]*m[6]*m[15]  + m[0]*m[7]*m[14]  + m[4]*m[2]*m[15] - m[4]*m[3]*m[14] - m[12]*m[2]*m[7]  + m[12]*m[3]*m[6];
    inv[10] =  m[0]*m[5]*m[15]  - m[0]*m[7]*m[13]  - m[4]*m[1]*m[15] + m[4]*m[3]*m[13] + m[12]*m[1]*m[7]  - m[12]*m[3]*m[5];
    inv[14] = -m[0]*m[5]*m[14]  + m[0]*m[6]*m[13]  + m[4]*m[1]*m[14] - m[4]*m[2]*m[13] - m[12]*m[1]*m[6]  + m[12]*m[2]*m[5];
    inv[3]  = -m[1]*m[6]*m[11]  + m[1]*m[7]*m[10]  + m[5]*m[2]*m[11] - m[5]*m[3]*m[10] - m[9]*m[2]*m[7]   + m[9]*m[3]*m[6];
    inv[7]  =  m[0]*m[6]*m[11]  - m[0]*m[7]*m[10]  - m[4]*m[2]*m[11] + m[4]*m[3]*m[10] + m[8]*m[2]*m[7]   - m[8]*m[3]*m[6];
    inv[11] = -m[0]*m[5]*m[11]  + m[0]*m[7]*m[9]   + m[4]*m[1]*m[11] - m[4]*m[3]*m[9]  - m[8]*m[1]*m[7]   + m[8]*m[3]*m[5];
    inv[15] =  m[0]*m[5]*m[10]  - m[0]*m[6]*m[9]   - m[4]*m[1]*m[10] + m[4]*m[2]*m[9]  + m[8]*m[1]*m[6]   - m[8]*m[2]*m[5];
    float det = m[0]*inv[0] + m[1]*inv[4] + m[2]*inv[8] + m[3]*inv[12];
    float rd = 1.0f/det;
    for (int k = 0; k < 16; ++k) inv[k] *= rd;
}

// Per-batch params: P[b*24 + 0..8]=A1, [9..17]=A2, [18..20]=p0
__global__ void setup_k(const float* __restrict__ rt_inv, const float* __restrict__ k_inv,
                        const float* __restrict__ sdd,    const float* __restrict__ iso,
                        const float* __restrict__ affine, const float* __restrict__ rot,
                        const float* __restrict__ xyz,    float* __restrict__ P,
                        float* __restrict__ zp, int B)
{
    int b = blockIdx.x * blockDim.x + threadIdx.x;
    if (blockIdx.x == 0 && threadIdx.x < 64) zp[threadIdx.x] = 0.0f;  // zero page
    if (b >= B) return;

    const float* Mi = rt_inv + (size_t)b * 16;
    float rt[16];
    inv4x4(Mi, rt);

    float c[3];
    for (int r = 0; r < 3; ++r)
        c[r] = rt[r*4+0]*iso[0] + rt[r*4+1]*iso[1] + rt[r*4+2]*iso[2] + rt[r*4+3];

    float rx = rot[b*3+0], ry = rot[b*3+1], rz = rot[b*3+2];
    float th = sqrtf(rx*rx + ry*ry + rz*rz);
    float Rr[9];
    if (th < 1e-8f) {
        Rr[0]=1.f; Rr[1]=0.f; Rr[2]=0.f;
        Rr[3]=0.f; Rr[4]=1.f; Rr[5]=0.f;
        Rr[6]=0.f; Rr[7]=0.f; Rr[8]=1.f;
    } else {
        float kx = rx/th, ky = ry/th, kz = rz/th;
        float s = sinf(th), ct = cosf(th), vv = 1.f - ct;
        Rr[0] = ct + vv*kx*kx;     Rr[1] = vv*kx*ky - s*kz;  Rr[2] = vv*kx*kz + s*ky;
        Rr[3] = vv*ky*kx + s*kz;   Rr[4] = ct + vv*ky*ky;    Rr[5] = vv*ky*kz - s*kx;
        Rr[6] = vv*kz*kx - s*ky;   Rr[7] = vv*kz*ky + s*kx;  Rr[8] = ct + vv*kz*kz;
    }

    float tp[3];
    for (int r = 0; r < 3; ++r)
        tp[r] = c[r] + xyz[b*3+r] - (Rr[r*3+0]*c[0] + Rr[r*3+1]*c[1] + Rr[r*3+2]*c[2]);

    float G[9], t[3];
    for (int r = 0; r < 3; ++r) {
        for (int cc = 0; cc < 3; ++cc)
            G[r*3+cc] = Mi[r*4+0]*Rr[0*3+cc] + Mi[r*4+1]*Rr[1*3+cc] + Mi[r*4+2]*Rr[2*3+cc];
        t[r] = Mi[r*4+0]*tp[0] + Mi[r*4+1]*tp[1] + Mi[r*4+2]*tp[2] + Mi[r*4+3];
    }

    float Ai[16];
    inv4x4(affine, Ai);

    float p0[3];
    for (int r = 0; r < 3; ++r)
        p0[r] = Ai[r*4+0]*t[0] + Ai[r*4+1]*t[1] + Ai[r*4+2]*t[2] + Ai[r*4+3];

    float MG[9];
    for (int r = 0; r < 3; ++r)
        for (int cc = 0; cc < 3; ++cc)
            MG[r*3+cc] = Ai[r*4+0]*G[0*3+cc] + Ai[r*4+1]*G[1*3+cc] + Ai[r*4+2]*G[2*3+cc];

    const float* Ki = k_inv + (size_t)b * 9;
    float sd = sdd[b];
    float* Pb = P + (size_t)b * 24;
    for (int r = 0; r < 3; ++r)
        for (int cc = 0; cc < 3; ++cc) {
            Pb[r*3+cc]     = (MG[r*3+0]*Ki[0*3+cc] + MG[r*3+1]*Ki[1*3+cc] + MG[r*3+2]*Ki[2*3+cc]) * sd;
            Pb[9 + r*3+cc] = (G[r*3+0]*Ki[0*3+cc]  + G[r*3+1]*Ki[1*3+cc]  + G[r*3+2]*Ki[2*3+cc])  * sd;
        }
    Pb[18] = p0[0]; Pb[19] = p0[1]; Pb[20] = p0[2];
}

__global__ void __launch_bounds__(256, 1) drr3(
        const float* __restrict__ vol, const float* __restrict__ P,
        const float* __restrict__ zp, float* __restrict__ out,
        const int* __restrict__ Hp, const int* __restrict__ Wp, const int* __restrict__ Sp,
        int B, int D)
{
    __shared__ float buf[2][BUFN];
    __shared__ int red[2][4][8];

    const int H = *Hp, W = *Wp, S = *Sp;
    const int npix = H * W;
    const int nTj = (W + TSZ - 1) / TSZ, nTi = (H + TSZ - 1) / TSZ;
    const int ntile = B * nTi * nTj;
    int bid = blockIdx.x;
    if (bid >= ntile) return;

    // bijective XCD-aware swizzle (m204)
    int q8 = ntile >> 3, r8 = ntile & 7;
    int xcd = bid & 7, idx = bid >> 3;
    int tile = (xcd < r8) ? xcd*(q8+1) + idx : r8*(q8+1) + (xcd - r8)*q8 + idx;
    int b = tile / (nTi * nTj);
    int trem = tile - b * (nTi * nTj);
    int ti = trem / nTj, tj = trem - ti * nTj;

    const int tid = threadIdx.x;
    const int wave = tid >> 6, lane = tid & 63;
    int u = tid >> 4, v = tid & 15;
    int r = ti * TSZ + u, c = tj * TSZ + v;
    bool pxok = (r < H) && (c < W);
    int rr = min(r, H - 1), cc = min(c, W - 1);

    const float* Pb = P + 24 * b;
    float px = cc + 0.5f, py = rr + 0.5f;
    float ddx = fmaf(Pb[0], px, fmaf(Pb[1], py, Pb[2]));
    float ddy = fmaf(Pb[3], px, fmaf(Pb[4], py, Pb[5]));
    float ddz = fmaf(Pb[6], px, fmaf(Pb[7], py, Pb[8]));
    float rxx = fmaf(Pb[9], px, fmaf(Pb[10], py, Pb[11]));
    float ryy = fmaf(Pb[12], px, fmaf(Pb[13], py, Pb[14]));
    float rzz = fmaf(Pb[15], px, fmaf(Pb[16], py, Pb[17]));
    float p0x = Pb[18], p0y = Pb[19], p0z = Pb[20];

    const float Sf = (float)S, invS = 1.0f / Sf;
    float seglen = sqrtf(rxx*rxx + ryy*ryy + rzz*rzz) * invS;
    const float LOW = -1.001f, HIW = (float)D + 0.001f;

    // per-thread slab clip of raw ray against widened support box
    float a0 = 0.f, a1 = 1.f;
    {
        float pp[3] = {p0x, p0y, p0z};
        float dd[3] = {ddx, ddy, ddz};
        #pragma unroll
        for (int ax = 0; ax < 3; ++ax) {
            if (fabsf(dd[ax]) > 1e-12f) {
                float ri = 1.0f / dd[ax];
                float t0 = (LOW - pp[ax]) * ri;
                float t1 = (HIW - pp[ax]) * ri;
                a0 = fmaxf(a0, fminf(t0, t1));
                a1 = fminf(a1, fmaxf(t0, t1));
            } else if (pp[ax] < LOW || pp[ax] > HIW) {
                a1 = -1.0f;
            }
        }
    }
    int slo = (int)ceilf(a0 * Sf - 0.5f) - 1;
    int shi = (int)floorf(a1 * Sf - 0.5f) + 1;

    // block-reduce step range -> red[1]
    {
        int m = slo, M = shi;
        #pragma unroll
        for (int o = 32; o; o >>= 1) {
            m = min(m, __shfl_xor(m, o, 64));
            M = max(M, __shfl_xor(M, o, 64));
        }
        if (lane == 0) { red[1][wave][0] = m; red[1][wave][1] = M; }
    }
    __syncthreads();
    int s_begin, s_end;
    {
        int m = red[1][0][0], M = red[1][0][1];
        for (int w = 1; w < 4; ++w) { m = min(m, red[1][w][0]); M = max(M, red[1][w][1]); }
        s_begin = max(m, 0);
        s_end   = min(M + 1, S);
    }
    int nchunk = (s_end > s_begin) ? (s_end - s_begin + CST - 1) / CST : 0;

    // coord eval: raw + support-clamped
    auto coords = [&](int s, float& x, float& y, float& z, float& cx, float& cy, float& cz) {
        float al = (s + 0.5f) * invS;
        x = fmaf(al, ddx, p0x); y = fmaf(al, ddy, p0y); z = fmaf(al, ddz, p0z);
        cx = fminf(fmaxf(x, LOW), HIW);
        cy = fminf(fmaxf(y, LOW), HIW);
        cz = fminf(fmaxf(z, LOW), HIW);
    };

    auto evalreduce = [&](int s0, int par) {
        int mnx = 0x7fffffff, mny = 0x7fffffff, mnz = 0x7fffffff;
        int mxx = -0x7fffffff, mxy = -0x7fffffff, mxz = -0x7fffffff;
        #pragma unroll
        for (int j = 0; j < CST; ++j) {
            float x, y, z, cx, cy, cz;
            coords(s0 + j, x, y, z, cx, cy, cz);
            int ix = (int)floorf(cx), iy = (int)floorf(cy), iz = (int)floorf(cz);
            mnx = min(mnx, ix); mxx = max(mxx, ix);
            mny = min(mny, iy); mxy = max(mxy, iy);
            mnz = min(mnz, iz); mxz = max(mxz, iz);
        }
        #pragma unroll
        for (int o = 32; o; o >>= 1) {
            mnx = min(mnx, __shfl_xor(mnx, o, 64)); mxx = max(mxx, __shfl_xor(mxx, o, 64));
            mny = min(mny, __shfl_xor(mny, o, 64)); mxy = max(mxy, __shfl_xor(mxy, o, 64));
            mnz = min(mnz, __shfl_xor(mnz, o, 64)); mxz = max(mxz, __shfl_xor(mxz, o, 64));
        }
        if (lane == 0) {
            red[par][wave][0] = mnx; red[par][wave][1] = mxx;
            red[par][wave][2] = mny; red[par][wave][3] = mxy;
            red[par][wave][4] = mnz; red[par][wave][5] = mxz;
        }
    };

    // box state (block-uniform)
    int bnx0=0, bny0=0, bza0=0, sy0=1, nrows0=0; bool fit0=false;

    auto finalize = [&](int par, int& bnx, int& bny, int& bza, int& sy, int& nrows, bool& fit) {
        int mnx = red[par][0][0], mxx = red[par][0][1];
        int mny = red[par][0][2], mxy = red[par][0][3];
        int mnz = red[par][0][4], mxz = red[par][0][5];
        for (int w = 1; w < 4; ++w) {
            mnx = min(mnx, red[par][w][0]); mxx = max(mxx, red[par][w][1]);
            mny = min(mny, red[par][w][2]); mxy = max(mxy, red[par][w][3]);
            mnz = min(mnz, red[par][w][4]); mxz = max(mxz, red[par][w][5]);
        }
        bnx = mnx; bny = mny; bza = mnz & ~3;
        int sx = mxx - mnx + 2;
        sy = (mxy - mny + 2) | 1;            // odd stride -> bank spread
        int zs = mxz + 1 - bza;              // max z word index used
        fit = (sx <= BXA) && (sy <= BYA) && (zs <= BZW - 1);
        nrows = sx * sy;
    };

    auto stage = [&](int par, int bnx, int bny, int bza, int sy, int nrows) {
        float* bb = buf[par];
        int G = nrows * 5;
        int N = (G + 63) >> 6;
        unsigned Msy = (1u << 20) / (unsigned)sy + 1u;
        for (int i = wave; i < N; i += 4) {
            int g = (i << 6) + lane;
            int row = (int)(((unsigned)g * 52429u) >> 18);   // g/5 exact for g<3100
            int gz = g - row * 5;
            int lx = (int)(((unsigned)row * Msy) >> 20);      // row/sy exact for row<=600
            int ly = row - lx * sy;
            int vx = bnx + lx, vy = bny + ly, vz = bza + (gz << 2);
            bool ok = (row < nrows) && ((unsigned)vx < (unsigned)D) &&
                      ((unsigned)vy < (unsigned)D) && ((unsigned)vz <= (unsigned)(D - 4));
            const float* src = ok ? (vol + (((size_t)vx * D + vy) * D + vz)) : zp;
            stage16(src, bb + (i << 8));
        }
    };

    float sum = 0.f;

    auto sampleLDS = [&](int par, int bnx, int bny, int bza, int sy, int s0) {
        const float* bc = buf[par];
        int xst = sy * BZW;
        #pragma unroll
        for (int j = 0; j < CST; ++j) {
            int s = s0 + j;
            float x, y, z, cx, cy, cz;
            coords(s, x, y, z, cx, cy, cz);
            float fx = floorf(cx), fy = floorf(cy), fz = floorf(cz);
            int ix = (int)fx, iy = (int)fy, iz = (int)fz;
            float tx = cx - fx, ty = cy - fy, tz = cz - fz;
            int base = (ix - bnx) * xst + (iy - bny) * BZW + (iz - bza);
            float v000 = bc[base],           v001 = bc[base + 1];
            float v010 = bc[base + BZW],     v011 = bc[base + BZW + 1];
            float v100 = bc[base + xst],     v101 = bc[base + xst + 1];
            float v110 = bc[base + xst + BZW], v111 = bc[base + xst + BZW + 1];
            float c00 = fmaf(tz, v001 - v000, v000);
            float c01 = fmaf(tz, v011 - v010, v010);
            float c10 = fmaf(tz, v101 - v100, v100);
            float c11 = fmaf(tz, v111 - v110, v110);
            float c0  = fmaf(ty, c01 - c00, c00);
            float c1  = fmaf(ty, c11 - c10, c10);
            float val = fmaf(tx, c1 - c0, c0);
            float act = ((x == cx) && (y == cy) && (z == cz) && (s < s_end)) ? 1.0f : 0.0f;
            sum = fmaf(act, val, sum);
        }
    };

    auto sampleGLB = [&](int s0) {   // cold fallback: direct gated global gathers
        const int D1 = D - 1;
        #pragma unroll
        for (int j = 0; j < CST; ++j) {
            int s = s0 + j;
            float x, y, z, cx, cy, cz;
            coords(s, x, y, z, cx, cy, cz);
            float fx = floorf(x), fy = floorf(y), fz = floorf(z);
            int ix = (int)fx, iy = (int)fy, iz = (int)fz;
            float tx = x - fx, ty = y - fy, tz = z - fz;
            int x0 = min(max(ix, 0), D1), x1 = min(max(ix + 1, 0), D1);
            int y0 = min(max(iy, 0), D1), y1 = min(max(iy + 1, 0), D1);
            int z0 = min(max(iz, 0), D1), z1 = min(max(iz + 1, 0), D1);
            bool bx0 = (unsigned)ix < (unsigned)D, bx1 = (unsigned)(ix+1) < (unsigned)D;
            bool by0 = (unsigned)iy < (unsigned)D, by1 = (unsigned)(iy+1) < (unsigned)D;
            bool bz0 = (unsigned)iz < (unsigned)D, bz1 = (unsigned)(iz+1) < (unsigned)D;
            const float* p00 = vol + ((size_t)x0 * D + y0) * D;
            const float* p01 = vol + ((size_t)x0 * D + y1) * D;
            const float* p10 = vol + ((size_t)x1 * D + y0) * D;
            const float* p11 = vol + ((size_t)x1 * D + y1) * D;
            float v000 = (bx0 && by0 && bz0) ? p00[z0] : 0.f;
            float v001 = (bx0 && by0 && bz1) ? p00[z1] : 0.f;
            float v010 = (bx0 && by1 && bz0) ? p01[z0] : 0.f;
            float v011 = (bx0 && by1 && bz1) ? p01[z1] : 0.f;
            float v100 = (bx1 && by0 && bz0) ? p10[z0] : 0.f;
            float v101 = (bx1 && by0 && bz1) ? p10[z1] : 0.f;
            float v110 = (bx1 && by1 && bz0) ? p11[z0] : 0.f;
            float v111 = (bx1 && by1 && bz1) ? p11[z1] : 0.f;
            float c00 = fmaf(tz, v001 - v000, v000);
            float c01 = fmaf(tz, v011 - v010, v010);
            float c10 = fmaf(tz, v101 - v100, v100);
            float c11 = fmaf(tz, v111 - v110, v110);
            float c0  = fmaf(ty, c01 - c00, c00);
            float c1  = fmaf(ty, c11 - c10, c10);
            float val = fmaf(tx, c1 - c0, c0);
            float act = (s < s_end) ? 1.0f : 0.0f;
            sum = fmaf(act, val, sum);
        }
    };

    if (nchunk > 0) {
        evalreduce(s_begin, 0);
        __syncthreads();
        finalize(0, bnx0, bny0, bza0, sy0, nrows0, fit0);
        if (fit0) stage(0, bnx0, bny0, bza0, sy0, nrows0);

        for (int k = 0; k < nchunk; ++k) {
            int par = k & 1, parn = par ^ 1;
            bool hasnext = (k + 1 < nchunk);
            if (hasnext) evalreduce(s_begin + (k + 1) * CST, parn);
            asm volatile("s_waitcnt vmcnt(0)" ::: "memory");
            __syncthreads();
            int bnx1=0, bny1=0, bza1=0, sy1=1, nrows1=0; bool fit1=false;
            if (hasnext) {
                finalize(parn, bnx1, bny1, bza1, sy1, nrows1, fit1);
                if (fit1) stage(parn, bnx1, bny1, bza1, sy1, nrows1);
            }
            int s0 = s_begin + k * CST;
            if (fit0) sampleLDS(par, bnx0, bny0, bza0, sy0, s0);
            else      sampleGLB(s0);
            bnx0 = bnx1; bny0 = bny1; bza0 = bza1; sy0 = sy1; nrows0 = nrows1; fit0 = fit1;
        }
    }

    if (pxok)
        out[(size_t)b * npix + (size_t)rr * W + cc] = sum * seglen;
}

extern "C" void kernel_launch(void* const* d_in, const int* in_sizes, int n_in,
                              void* d_out, int out_size, void* d_ws, size_t ws_size,
                              hipStream_t stream)
{
    const float* volume = (const float*)d_in[0];
    const float* rt_inv = (const float*)d_in[1];
    const float* k_inv  = (const float*)d_in[2];
    const float* sdd    = (const float*)d_in[3];
    const float* iso    = (const float*)d_in[4];
    const float* affine = (const float*)d_in[5];
    const float* rot    = (const float*)d_in[6];
    const float* xyz    = (const float*)d_in[7];
    const int*   Hp     = (const int*)d_in[8];
    const int*   Wp     = (const int*)d_in[9];
    const int*   Sp     = (const int*)d_in[10];

    int B = in_sizes[1] / 16;                         // rt_inv is (B,4,4)
    int D = (int)lroundf(cbrtf((float)in_sizes[0]));  // volume is (D,D,D)

    float* P  = (float*)d_ws;                         // 24 floats per batch
    float* zp = (float*)((char*)d_ws + ((24 * B * 4 + 1023) & ~1023) + 1024); // 256B zero page

    setup_k<<<(B + 63) / 64, 64, 0, stream>>>(rt_inv, k_inv, sdd, iso, affine, rot, xyz, P, zp, B);

    // one block per 16x16 output tile
    long long hw = (long long)out_size / B;
    int H = 0, W = 0;
    // H,W only known on device; grid needs a host-side bound: use out_size.
    // tiles = B * ceil(H/16)*ceil(W/16) <= B * ceil(hw/256) + slack; launch exact
    // bound assuming H,W multiples-of-anything: ceil over both dims <=
    // (H/16+1)*(W/16+1) — use a safe upper bound and guard in-kernel.
    long long maxtiles = (long long)B * ((hw + 255) / 256 + ((hw > 0) ? 2 * (long long)sqrt((double)hw) / 16 + 2 : 0));
    if (maxtiles < 1) maxtiles = 1;
    if (maxtiles > (1 << 20)) maxtiles = (1 << 20);
    drr3<<<(int)maxtiles, 256, 0, stream>>>(volume, P, zp, (float*)d_out, Hp, Wp, Sp, B, D);
    (void)H; (void)W; (void)ws_size; (void)n_in;
}

// Round 5
// 38.809 us; speedup vs baseline: 1.5301x; 1.5301x over previous
//
#include <hip/hip_runtime.h>
#include <math.h>

// ---------------------------------------------------------------------------
// DRR forward projection: per-pixel ray march through D^3 volume, trilinear.
//
// setup_k: folds all small linear algebra into 21 per-batch floats:
//   vox(s) = p0 + alpha_s*(A1@pixh), ray = A2@pixh, seglen = |ray|/S.
//
// drr4: 1 wave = 4 pixels (1x4 strip), 16 lanes/pixel striding over steps.
//   - analytic slab clip to the (-1,D) support box (outside = exact 0)
//   - PHASE-SPLIT main loop: phase A issues all 24 pair-gathers into a
//     statically-indexed register array (forces 24 outstanding loads/wave,
//     true MLP; round-3's VGPR=40 showed the compiler had serialized them
//     ~4 deep); phase B consumes in issue order (descending vmcnt waits).
//   - z-corner pair loaded as one 8B load (clamped base + branchless select)
//   - x/y out-of-bounds folded into lerp weights (matches reference inb)
//   - XCD-aware 64x64-pixel supertile swizzle (halved FETCH_SIZE in r3)
// ---------------------------------------------------------------------------

typedef float f2 __attribute__((ext_vector_type(2), aligned(4)));

__device__ __forceinline__ void inv4x4(const float* m, float* inv) {
    inv[0]  =  m[5]*m[10]*m[15] - m[5]*m[11]*m[14] - m[9]*m[6]*m[15] + m[9]*m[7]*m[14] + m[13]*m[6]*m[11] - m[13]*m[7]*m[10];
    inv[4]  = -m[4]*m[10]*m[15] + m[4]*m[11]*m[14] + m[8]*m[6]*m[15] - m[8]*m[7]*m[14] - m[12]*m[6]*m[11] + m[12]*m[7]*m[10];
    inv[8]  =  m[4]*m[9]*m[15]  - m[4]*m[11]*m[13] - m[8]*m[5]*m[15] + m[8]*m[7]*m[13] + m[12]*m[5]*m[11] - m[12]*m[7]*m[9];
    inv[12] = -m[4]*m[9]*m[14]  + m[4]*m[10]*m[13] + m[8]*m[5]*m[14] - m[8]*m[6]*m[13] - m[12]*m[5]*m[10] + m[12]*m[6]*m[9];
    inv[1]  = -m[1]*m[10]*m[15] + m[1]*m[11]*m[14] + m[9]*m[2]*m[15] - m[9]*m[3]*m[14] - m[13]*m[2]*m[11] + m[13]*m[3]*m[10];
    inv[5]  =  m[0]*m[10]*m[15] - m[0]*m[11]*m[14] - m[8]*m[2]*m[15] + m[8]*m[3]*m[14] + m[12]*m[2]*m[11] - m[12]*m[3]*m[10];
    inv[9]  = -m[0]*m[9]*m[15]  + m[0]*m[11]*m[13] + m[8]*m[1]*m[15] - m[8]*m[3]*m[13] - m[12]*m[1]*m[11] + m[12]*m[3]*m[9];
    inv[13] =  m[0]*m[9]*m[14]  - m[0]*m[10]*m[13] - m[8]*m[1]*m[14] + m[8]*m[2]*m[13] + m[12]*m[1]*m[10] - m[12]*m[2]*m[9];
    inv[2]  =  m[1]*m[6]*m[15]  - m[1]*m[7]*m[14]  - m[5]*m[2]*m[15] + m[5]*m[3]*m[14] + m[13]*m[2]*m[7]  - m[13]*m[3]*m[6];
    inv[6]  = -m[0]*m[6]*m[15]  + m[0]*m[7]*m[14]  + m[4]*m[2]*m[15] - m[4]*m[3]*m[14] - m[12]*m[2]*m[7]  + m[12]*m[3]*m[6];
    inv[10] =  m[0]*m[5]*m[15]  - m[0]*m[7]*m[13]  - m[4]*m[1]*m[15] + m[4]*m[3]*m[13] + m[12]*m[1]*m[7]  - m[12]*m[3]*m[5];
    inv[14] = -m[0]*m[5]*m[14]  + m[0]*m[6]*m[13]  + m[4]*m[1]*m[14] - m[4]*m[2]*m[13] - m[12]*m[1]*m[6]  + m[12]*m[2]*m[5];
    inv[3]  = -m[1]*m[6]*m[11]  + m[1]*m[7]*m[10]  + m[5]*m[2]*m[11] - m[5]*m[3]*m[10] - m[9]*m[2]*m[7]   + m[9]*m[3]*m[6];
    inv[7]  =  m[0]*m[6]*m[11]  - m[0]*m[7]*m[10]  - m[4]*m[2]*m[11] + m[4]*m[3]*m[10] + m[8]*m[2]*m[7]   - m[8]*m[3]*m[6];
    inv[11] = -m[0]*m[5]*m[11]  + m[0]*m[7]*m[9]   + m[4]*m[1]*m[11] - m[4]*m[3]*m[9]  - m[8]*m[1]*m[7]   + m[8]*m[3]*m[5];
    inv[15] =  m[0]*m[5]*m[10]  - m[0]*m[6]*m[9]   - m[4]*m[1]*m[10] + m[4]*m[2]*m[9]  + m[8]*m[1]*m[6]   - m[8]*m[2]*m[5];
    float det = m[0]*inv[0] + m[1]*inv[4] + m[2]*inv[8] + m[3]*inv[12];
    float rd = 1.0f/det;
    for (int k = 0; k < 16; ++k) inv[k] *= rd;
}

// Per-batch params: P[b*24 + 0..8]=A1, [9..17]=A2, [18..20]=p0
__global__ void setup_k(const float* __restrict__ rt_inv, const float* __restrict__ k_inv,
                        const float* __restrict__ sdd,    const float* __restrict__ iso,
                        const float* __restrict__ affine, const float* __restrict__ rot,
                        const float* __restrict__ xyz,    float* __restrict__ P, int B)
{
    int b = blockIdx.x * blockDim.x + threadIdx.x;
    if (b >= B) return;

    const float* Mi = rt_inv + (size_t)b * 16;
    float rt[16];
    inv4x4(Mi, rt);

    float c[3];
    for (int r = 0; r < 3; ++r)
        c[r] = rt[r*4+0]*iso[0] + rt[r*4+1]*iso[1] + rt[r*4+2]*iso[2] + rt[r*4+3];

    float rx = rot[b*3+0], ry = rot[b*3+1], rz = rot[b*3+2];
    float th = sqrtf(rx*rx + ry*ry + rz*rz);
    float Rr[9];
    if (th < 1e-8f) {
        Rr[0]=1.f; Rr[1]=0.f; Rr[2]=0.f;
        Rr[3]=0.f; Rr[4]=1.f; Rr[5]=0.f;
        Rr[6]=0.f; Rr[7]=0.f; Rr[8]=1.f;
    } else {
        float kx = rx/th, ky = ry/th, kz = rz/th;
        float s = sinf(th), ct = cosf(th), v = 1.f - ct;
        Rr[0] = ct + v*kx*kx;     Rr[1] = v*kx*ky - s*kz;  Rr[2] = v*kx*kz + s*ky;
        Rr[3] = v*ky*kx + s*kz;   Rr[4] = ct + v*ky*ky;    Rr[5] = v*ky*kz - s*kx;
        Rr[6] = v*kz*kx - s*ky;   Rr[7] = v*kz*ky + s*kx;  Rr[8] = ct + v*kz*kz;
    }

    float tp[3];
    for (int r = 0; r < 3; ++r)
        tp[r] = c[r] + xyz[b*3+r] - (Rr[r*3+0]*c[0] + Rr[r*3+1]*c[1] + Rr[r*3+2]*c[2]);

    float G[9], t[3];
    for (int r = 0; r < 3; ++r) {
        for (int cc = 0; cc < 3; ++cc)
            G[r*3+cc] = Mi[r*4+0]*Rr[0*3+cc] + Mi[r*4+1]*Rr[1*3+cc] + Mi[r*4+2]*Rr[2*3+cc];
        t[r] = Mi[r*4+0]*tp[0] + Mi[r*4+1]*tp[1] + Mi[r*4+2]*tp[2] + Mi[r*4+3];
    }

    float Ai[16];
    inv4x4(affine, Ai);

    float p0[3];
    for (int r = 0; r < 3; ++r)
        p0[r] = Ai[r*4+0]*t[0] + Ai[r*4+1]*t[1] + Ai[r*4+2]*t[2] + Ai[r*4+3];

    float MG[9];
    for (int r = 0; r < 3; ++r)
        for (int cc = 0; cc < 3; ++cc)
            MG[r*3+cc] = Ai[r*4+0]*G[0*3+cc] + Ai[r*4+1]*G[1*3+cc] + Ai[r*4+2]*G[2*3+cc];

    const float* Ki = k_inv + (size_t)b * 9;
    float sd = sdd[b];
    float* Pb = P + (size_t)b * 24;
    for (int r = 0; r < 3; ++r)
        for (int cc = 0; cc < 3; ++cc) {
            Pb[r*3+cc]     = (MG[r*3+0]*Ki[0*3+cc] + MG[r*3+1]*Ki[1*3+cc] + MG[r*3+2]*Ki[2*3+cc]) * sd;
            Pb[9 + r*3+cc] = (G[r*3+0]*Ki[0*3+cc]  + G[r*3+1]*Ki[1*3+cc]  + G[r*3+2]*Ki[2*3+cc])  * sd;
        }
    Pb[18] = p0[0]; Pb[19] = p0[1]; Pb[20] = p0[2];
}

// 1 wave = 4 pixels (1x4 strip); lane = 16*p + t; lane t strides steps.
// Block (256 thr, 4 waves) owns a 4x4 pixel patch; 256 blocks = one 64x64
// supertile; supertiles chunked per XCD.
__global__ void __launch_bounds__(256, 4) drr4(
        const float* __restrict__ vol, const float* __restrict__ P,
        float* __restrict__ out,
        const int* __restrict__ Hp, const int* __restrict__ Wp, const int* __restrict__ Sp,
        int B, int D)
{
    const int H = *Hp, W = *Wp, S = *Sp;
    const int npix = H * W;
    const int nSj = (W + 63) >> 6, nSi = (H + 63) >> 6;
    const int nS = nSi * nSj;
    const int nStot = B * nS;
    const long long nVB = (long long)nStot << 8;   // 256 blocks per supertile

    const int tid  = threadIdx.x;
    const int wave = tid >> 6, lane = tid & 63;
    const int p    = lane >> 4, t = lane & 15;
    const int D1   = D - 1;
    const float Sf = (float)S, invS = 1.0f / Sf;

    for (long long vb = blockIdx.x; vb < nVB; vb += gridDim.x) {
        int st, within;
        if ((nStot & 7) == 0) {
            int xcd = (int)(vb & 7);
            long long slot = vb >> 3;
            st = xcd * (nStot >> 3) + (int)(slot >> 8);
            within = (int)(slot & 255);
        } else {
            st = (int)(vb >> 8);
            within = (int)(vb & 255);
        }
        int b = 0, stl = st;
        if (B > 1) { b = st / nS; stl = st - b * nS; }
        int si = stl / nSj, sj = stl - si * nSj;

        int r0 = (si << 6) + ((within >> 4) << 2) + wave;   // row
        int c0 = (sj << 6) + ((within & 15) << 2) + p;      // col
        bool valid = (r0 < H) && (c0 < W);
        int rr = min(r0, H - 1), cc = min(c0, W - 1);

        const float* Pb = P + 24 * __builtin_amdgcn_readfirstlane(b);
        float px = cc + 0.5f, py = rr + 0.5f;
        float ddx = fmaf(Pb[0], px, fmaf(Pb[1], py, Pb[2]));
        float ddy = fmaf(Pb[3], px, fmaf(Pb[4], py, Pb[5]));
        float ddz = fmaf(Pb[6], px, fmaf(Pb[7], py, Pb[8]));
        float rxx = fmaf(Pb[9], px, fmaf(Pb[10], py, Pb[11]));
        float ryy = fmaf(Pb[12], px, fmaf(Pb[13], py, Pb[14]));
        float rzz = fmaf(Pb[15], px, fmaf(Pb[16], py, Pb[17]));
        float p0x = Pb[18], p0y = Pb[19], p0z = Pb[20];

        float seglen = sqrtf(rxx*rxx + ryy*ryy + rzz*rzz) * invS;

        // slab clip to support box (-1, D), widened
        const float lo = -1.001f, hi = (float)D + 0.001f;
        float a0 = 0.f, a1 = 1.f;
        {
            float pp[3] = {p0x, p0y, p0z};
            float dd[3] = {ddx, ddy, ddz};
            #pragma unroll
            for (int ax = 0; ax < 3; ++ax) {
                if (fabsf(dd[ax]) > 1e-12f) {
                    float r  = 1.0f / dd[ax];
                    float t0 = (lo - pp[ax]) * r;
                    float t1 = (hi - pp[ax]) * r;
                    a0 = fmaxf(a0, fminf(t0, t1));
                    a1 = fminf(a1, fmaxf(t0, t1));
                } else if (pp[ax] < lo || pp[ax] > hi) {
                    a1 = -1.0f;
                }
            }
        }
        int slo = (int)ceilf(a0 * Sf - 0.5f) - 1;
        int shi = (int)floorf(a1 * Sf - 0.5f) + 1;
        if (slo < 0) slo = 0;
        if (shi > S - 1) shi = S - 1;

        float sum = 0.f;

        // ---- phase-split main block: 6 samples/thread, 24 loads in flight ----
        {
            f2    q[24];
            float xs[6], ys[6], zs[6];

            #pragma unroll
            for (int it = 0; it < 6; ++it) {
                int s = slo + t + (it << 4);
                float al = (s + 0.5f) * invS;
                float x = fmaf(al, ddx, p0x);
                float y = fmaf(al, ddy, p0y);
                float z = fmaf(al, ddz, p0z);
                xs[it] = x; ys[it] = y; zs[it] = z;
                int ix = (int)floorf(x), iy = (int)floorf(y), iz = (int)floorf(z);
                int x0c = min(max(ix, 0), D1), x1c = min(max(ix + 1, 0), D1);
                int y0c = min(max(iy, 0), D1), y1c = min(max(iy + 1, 0), D1);
                int z0c = min(max(iz, 0), D - 2);
                int a0r = x0c * D, a1r = x1c * D;
                q[it*4+0] = *(const f2*)(vol + (unsigned)((a0r + y0c) * D + z0c));
                q[it*4+1] = *(const f2*)(vol + (unsigned)((a0r + y1c) * D + z0c));
                q[it*4+2] = *(const f2*)(vol + (unsigned)((a1r + y0c) * D + z0c));
                q[it*4+3] = *(const f2*)(vol + (unsigned)((a1r + y1c) * D + z0c));
            }

            #pragma unroll
            for (int it = 0; it < 6; ++it) {
                int s = slo + t + (it << 4);
                float act = (s <= shi) ? 1.0f : 0.0f;
                float x = xs[it], y = ys[it], z = zs[it];
                float fx = floorf(x), fy = floorf(y), fz = floorf(z);
                int ix = (int)fx, iy = (int)fy, iz = (int)fz;
                float tx = x - fx, ty = y - fy, tz = z - fz;
                int z0c = min(max(iz, 0), D - 2);
                bool e0 = (iz == z0c), em = (iz == z0c - 1), ep = (iz == z0c + 1);
                f2 q00 = q[it*4+0], q01 = q[it*4+1], q10 = q[it*4+2], q11 = q[it*4+3];
                float v0, v1, c00, c01, c10, c11;
                v0 = e0 ? q00.x : (ep ? q00.y : 0.f);
                v1 = e0 ? q00.y : (em ? q00.x : 0.f);
                c00 = fmaf(tz, v1 - v0, v0);
                v0 = e0 ? q01.x : (ep ? q01.y : 0.f);
                v1 = e0 ? q01.y : (em ? q01.x : 0.f);
                c01 = fmaf(tz, v1 - v0, v0);
                v0 = e0 ? q10.x : (ep ? q10.y : 0.f);
                v1 = e0 ? q10.y : (em ? q10.x : 0.f);
                c10 = fmaf(tz, v1 - v0, v0);
                v0 = e0 ? q11.x : (ep ? q11.y : 0.f);
                v1 = e0 ? q11.y : (em ? q11.x : 0.f);
                c11 = fmaf(tz, v1 - v0, v0);
                float wy0 = ((unsigned)iy       < (unsigned)D) ? 1.f - ty : 0.f;
                float wy1 = ((unsigned)(iy + 1) < (unsigned)D) ? ty       : 0.f;
                float wx0 = ((unsigned)ix       < (unsigned)D) ? 1.f - tx : 0.f;
                float wx1 = ((unsigned)(ix + 1) < (unsigned)D) ? tx       : 0.f;
                float s0 = fmaf(wy0, c00, wy1 * c01);
                float s1 = fmaf(wy0, c10, wy1 * c11);
                sum = fmaf(act * wx0, s0, sum);
                sum = fmaf(act * wx1, s1, sum);
            }
        }

        // generic tail (never taken for paths <= 96 steps)
        for (int s = slo + 96 + t; s <= shi; s += 16) {
            float al = (s + 0.5f) * invS;
            float x = fmaf(al, ddx, p0x);
            float y = fmaf(al, ddy, p0y);
            float z = fmaf(al, ddz, p0z);
            float fx = floorf(x), fy = floorf(y), fz = floorf(z);
            int ix = (int)fx, iy = (int)fy, iz = (int)fz;
            float tx = x - fx, ty = y - fy, tz = z - fz;
            int x0c = min(max(ix, 0), D1), x1c = min(max(ix + 1, 0), D1);
            int y0c = min(max(iy, 0), D1), y1c = min(max(iy + 1, 0), D1);
            int z0c = min(max(iz, 0), D - 2);
            int a0r = x0c * D, a1r = x1c * D;
            f2 q00 = *(const f2*)(vol + (unsigned)((a0r + y0c) * D + z0c));
            f2 q01 = *(const f2*)(vol + (unsigned)((a0r + y1c) * D + z0c));
            f2 q10 = *(const f2*)(vol + (unsigned)((a1r + y0c) * D + z0c));
            f2 q11 = *(const f2*)(vol + (unsigned)((a1r + y1c) * D + z0c));
            bool e0 = (iz == z0c), em = (iz == z0c - 1), ep = (iz == z0c + 1);
            float v0, v1, c00, c01, c10, c11;
            v0 = e0 ? q00.x : (ep ? q00.y : 0.f);
            v1 = e0 ? q00.y : (em ? q00.x : 0.f);
            c00 = fmaf(tz, v1 - v0, v0);
            v0 = e0 ? q01.x : (ep ? q01.y : 0.f);
            v1 = e0 ? q01.y : (em ? q01.x : 0.f);
            c01 = fmaf(tz, v1 - v0, v0);
            v0 = e0 ? q10.x : (ep ? q10.y : 0.f);
            v1 = e0 ? q10.y : (em ? q10.x : 0.f);
            c10 = fmaf(tz, v1 - v0, v0);
            v0 = e0 ? q11.x : (ep ? q11.y : 0.f);
            v1 = e0 ? q11.y : (em ? q11.x : 0.f);
            c11 = fmaf(tz, v1 - v0, v0);
            float wy0 = ((unsigned)iy       < (unsigned)D) ? 1.f - ty : 0.f;
            float wy1 = ((unsigned)(iy + 1) < (unsigned)D) ? ty       : 0.f;
            float wx0 = ((unsigned)ix       < (unsigned)D) ? 1.f - tx : 0.f;
            float wx1 = ((unsigned)(ix + 1) < (unsigned)D) ? tx       : 0.f;
            float s0 = fmaf(wy0, c00, wy1 * c01);
            float s1 = fmaf(wy0, c10, wy1 * c11);
            sum = fmaf(wx0, s0, sum);
            sum = fmaf(wx1, s1, sum);
        }

        sum += __shfl_xor(sum, 8, 16);
        sum += __shfl_xor(sum, 4, 16);
        sum += __shfl_xor(sum, 2, 16);
        sum += __shfl_xor(sum, 1, 16);

        if (t == 0 && valid)
            out[(size_t)b * npix + (size_t)rr * W + cc] = sum * seglen;
    }
}

extern "C" void kernel_launch(void* const* d_in, const int* in_sizes, int n_in,
                              void* d_out, int out_size, void* d_ws, size_t ws_size,
                              hipStream_t stream)
{
    const float* volume = (const float*)d_in[0];
    const float* rt_inv = (const float*)d_in[1];
    const float* k_inv  = (const float*)d_in[2];
    const float* sdd    = (const float*)d_in[3];
    const float* iso    = (const float*)d_in[4];
    const float* affine = (const float*)d_in[5];
    const float* rot    = (const float*)d_in[6];
    const float* xyz    = (const float*)d_in[7];
    const int*   Hp     = (const int*)d_in[8];
    const int*   Wp     = (const int*)d_in[9];
    const int*   Sp     = (const int*)d_in[10];

    int B = in_sizes[1] / 16;                         // rt_inv is (B,4,4)
    int D = (int)lroundf(cbrtf((float)in_sizes[0]));  // volume is (D,D,D)

    float* P = (float*)d_ws;
    setup_k<<<(B + 63) / 64, 64, 0, stream>>>(rt_inv, k_inv, sdd, iso, affine, rot, xyz, P, B);

    // one block per 4x4-pixel patch via device-side supertile walk
    long long hw = (long long)out_size / B;
    long long vbl = (long long)B * ((hw + 4095) >> 12) * 256;
    if (vbl > (1 << 22)) vbl = (1 << 22);
    drr4<<<(int)vbl, 256, 0, stream>>>(volume, P, (float*)d_out, Hp, Wp, Sp, B, D);
    (void)n_in; (void)ws_size;
}